// Round 4
// baseline (2598.628 us; speedup 1.0000x reference)
//
#include <hip/hip_runtime.h>

typedef unsigned short u16;
typedef unsigned int   u32;

#define B_  64
#define T_  300
#define V_  25
#define C_  64
#define ROWS (B_*T_)          // 19200
#define ROWE (V_*C_)          // 1600
#define STR  3200             // u16 stride of one fp32 output row slot
#define NSTAT 480000.0f       // B*T*V
#define EPS_ 1e-5f

__device__ __forceinline__ float b2f(u16 u) {
    union { u32 i; float f; } v; v.i = ((u32)u) << 16; return v.f;
}
__device__ __forceinline__ u16 f2b(float f) {  // round-to-nearest-even
    union { float f; u32 i; } v; v.f = f;
    u32 x = v.i;
    u32 r = x + 0x7fffu + ((x >> 16) & 1u);
    return (u16)(r >> 16);
}
// unpack a (hi<<16)|lo bf16 pair
__device__ __forceinline__ float plo(u32 p) {
    union { u32 i; float f; } v; v.i = p << 16; return v.f;
}
__device__ __forceinline__ float phi(u32 p) {
    union { u32 i; float f; } v; v.i = p & 0xffff0000u; return v.f;
}

// ---------------------------------------------------------------------------
// K1: An[3][25][28] fp32 (gcn_norm, unit diag), bsum=b1+b2+b3, and bf16-pair
// packed weights wPack[3][32][64], wtPack[32][64] (u32 = k+1<<16 | k).
// ---------------------------------------------------------------------------
__global__ void k1_prep(const float* __restrict__ A, const float* __restrict__ E,
                        const float* __restrict__ b1, const float* __restrict__ b2,
                        const float* __restrict__ b3,
                        const float* __restrict__ W1, const float* __restrict__ W2,
                        const float* __restrict__ W3, const float* __restrict__ Wt,
                        float* __restrict__ an, float* __restrict__ bsum,
                        u32* __restrict__ wPack, u32* __restrict__ wtPack)
{
    __shared__ float dinvL[75];
    const int tid = threadIdx.x;
    if (tid < 75) {
        int i = tid / 25, v = tid % 25;
        float d = 1.0f;                       // diagonal forced to 1
        for (int u = 0; u < 25; ++u)
            if (u != v) d += A[(i*25+v)*25+u] * E[(i*25+v)*25+u];
        dinvL[tid] = (d > 0.0f) ? rsqrtf(d) : 0.0f;
    }
    __syncthreads();
    for (int idx = tid; idx < 2112; idx += 128) {
        float val = 0.0f;
        if (idx < 2100) {
            int i = idx / 700, rem = idx % 700, v = rem / 28, u = rem % 28;
            if (u < 25) {
                float ad = (u == v) ? 1.0f : A[(i*25+v)*25+u] * E[(i*25+v)*25+u];
                val = dinvL[i*25+v] * ad * dinvL[i*25+u];
            }
        }
        an[idx] = val;
    }
    if (tid < 64) bsum[tid] = b1[tid] + b2[tid] + b3[tid];

    for (int idx = tid; idx < 6144; idx += 128) {
        const int br = idx >> 11, rem = idx & 2047, k2 = rem >> 6, c = rem & 63;
        const float* Wsrc = (br == 0) ? W1 : ((br == 1) ? W2 : W3);
        const u32 lo = f2b(Wsrc[(2*k2)*64 + c]);
        const u32 hi = f2b(Wsrc[(2*k2+1)*64 + c]);
        wPack[idx] = lo | (hi << 16);
    }
    for (int idx = tid; idx < 2048; idx += 128) {
        const int k2 = idx >> 6, c = idx & 63;
        const u32 lo = f2b(Wt[(2*k2)*64 + c]);
        const u32 hi = f2b(Wt[(2*k2+1)*64 + c]);
        wtPack[idx] = lo | (hi << 16);
    }
}

// ---------------------------------------------------------------------------
// K2: spatial. Per row: out1 = sum_br An_br @ (x @ W_br) + bsum.
// 2 rows/block, branch-outer loop, acc2 in regs. out1 -> bf16 into the LOW
// half of each fp32 d_out row slot. BN1 partials per block.
// LDS = 8K(wp) + 8.4K(an) + 12.8K(x fp32) + 2x3.3K(xw bf16) + 2K = 37.8 KB
// -> 4 blocks/CU (was 2-3).
// ---------------------------------------------------------------------------
__global__ __launch_bounds__(256) void k2_spatial(
    const float* __restrict__ x,
    const u32* __restrict__ wPack,
    const float* __restrict__ an, const float* __restrict__ bsum,
    u16* out1, float* __restrict__ p1)
{
    __shared__ u32   wpL[2048];                     // current branch W packed
    __shared__ __align__(16) float anL[2112];       // [3][25][28]
    __shared__ __align__(16) float xL[3200];        // 2 rows fp32
    __shared__ u16   xwL[2][25*66];                 // x@W handoff, bf16
    __shared__ float redL[512];

    const int tid = threadIdx.x, c = tid & 63, g = tid >> 6;
    const int r0 = blockIdx.x * 2;

    for (int i2 = tid; i2 < 2112; i2 += 256) anL[i2] = an[i2];
    {   // stage 2 rows of x (fp32, float4)
        const float4* xg = (const float4*)&x[(size_t)r0 * ROWE];
        float4* xs = (float4*)xL;
        for (int i2 = tid; i2 < 800; i2 += 256) xs[i2] = xg[i2];
    }
    const float bsv = bsum[c];
    float acc2[2][7];
    #pragma unroll
    for (int r = 0; r < 2; ++r)
        #pragma unroll
        for (int j = 0; j < 7; ++j) acc2[r][j] = bsv;
    float ssum = 0.0f, ssq = 0.0f;

    for (int br = 0; br < 3; ++br) {
        // stage this branch's packed W (overlaps previous A' phase)
        {
            const u32* wg = &wPack[br * 2048];
            for (int i2 = tid; i2 < 2048; i2 += 256) wpL[i2] = wg[i2];
        }
        __syncthreads();   // wpL (+ anL/xL first iter) ready

        // ---- GEMM1 row 0 -> xw0 ----
        {
            float acc[7];
            #pragma unroll
            for (int j = 0; j < 7; ++j) acc[j] = 0.0f;
            #pragma unroll 4
            for (int k4 = 0; k4 < 16; ++k4) {
                const int k = k4 * 4;
                const u32 p0 = wpL[(k4*2)*64 + c], p1v = wpL[(k4*2+1)*64 + c];
                const float w0 = plo(p0), w1 = phi(p0);
                const float w2 = plo(p1v), w3 = phi(p1v);
                #pragma unroll
                for (int j = 0; j < 7; ++j) {
                    const int u = g + 4*j;
                    if (u < 25) {
                        const float4 xv = *(const float4*)&xL[u*64 + k];
                        acc[j] = fmaf(xv.x, w0, fmaf(xv.y, w1,
                                 fmaf(xv.z, w2, fmaf(xv.w, w3, acc[j]))));
                    }
                }
            }
            #pragma unroll
            for (int j = 0; j < 7; ++j) {
                const int u = g + 4*j;
                if (u < 25) xwL[0][u*66 + c] = f2b(acc[j]);
            }
        }
        __syncthreads();   // xw0 visible

        // ---- A'(row0) + GEMM1 row 1 -> xw1 (disjoint buffers) ----
        {
            float xv[25];
            #pragma unroll
            for (int u = 0; u < 25; ++u) xv[u] = b2f(xwL[0][u*66 + c]);
            #pragma unroll
            for (int j = 0; j < 7; ++j) {
                const int v = g + 4*j;
                if (v < 25) {
                    const float* ar = &anL[(br*25+v)*28];
                    float a0 = 0.0f;
                    #pragma unroll
                    for (int u4 = 0; u4 < 6; ++u4) {
                        const float4 a4 = *(const float4*)&ar[u4*4];
                        a0 = fmaf(a4.x, xv[u4*4+0], a0);
                        a0 = fmaf(a4.y, xv[u4*4+1], a0);
                        a0 = fmaf(a4.z, xv[u4*4+2], a0);
                        a0 = fmaf(a4.w, xv[u4*4+3], a0);
                    }
                    a0 = fmaf(ar[24], xv[24], a0);
                    acc2[0][j] += a0;
                }
            }
        }
        {
            float acc[7];
            #pragma unroll
            for (int j = 0; j < 7; ++j) acc[j] = 0.0f;
            #pragma unroll 4
            for (int k4 = 0; k4 < 16; ++k4) {
                const int k = k4 * 4;
                const u32 p0 = wpL[(k4*2)*64 + c], p1v = wpL[(k4*2+1)*64 + c];
                const float w0 = plo(p0), w1 = phi(p0);
                const float w2 = plo(p1v), w3 = phi(p1v);
                #pragma unroll
                for (int j = 0; j < 7; ++j) {
                    const int u = g + 4*j;
                    if (u < 25) {
                        const float4 xv = *(const float4*)&xL[1600 + u*64 + k];
                        acc[j] = fmaf(xv.x, w0, fmaf(xv.y, w1,
                                 fmaf(xv.z, w2, fmaf(xv.w, w3, acc[j]))));
                    }
                }
            }
            #pragma unroll
            for (int j = 0; j < 7; ++j) {
                const int u = g + 4*j;
                if (u < 25) xwL[1][u*66 + c] = f2b(acc[j]);
            }
        }
        __syncthreads();   // xw1 visible; wpL reads done -> next stage safe

        // ---- A'(row1) (next branch's wpL stage overlaps this) ----
        {
            float xv[25];
            #pragma unroll
            for (int u = 0; u < 25; ++u) xv[u] = b2f(xwL[1][u*66 + c]);
            #pragma unroll
            for (int j = 0; j < 7; ++j) {
                const int v = g + 4*j;
                if (v < 25) {
                    const float* ar = &anL[(br*25+v)*28];
                    float a0 = 0.0f;
                    #pragma unroll
                    for (int u4 = 0; u4 < 6; ++u4) {
                        const float4 a4 = *(const float4*)&ar[u4*4];
                        a0 = fmaf(a4.x, xv[u4*4+0], a0);
                        a0 = fmaf(a4.y, xv[u4*4+1], a0);
                        a0 = fmaf(a4.z, xv[u4*4+2], a0);
                        a0 = fmaf(a4.w, xv[u4*4+3], a0);
                    }
                    a0 = fmaf(ar[24], xv[24], a0);
                    acc2[1][j] += a0;
                }
            }
        }
        // note: GEMM1(row0) of next branch writes xw0, last read 2 barriers ago
    }

    // epilogue: stats + bf16 store to low halves
    #pragma unroll
    for (int r = 0; r < 2; ++r) {
        const int row = r0 + r;
        #pragma unroll
        for (int j = 0; j < 7; ++j) {
            const int v = g + 4*j;
            if (v < 25) {
                const float zz = acc2[r][j];
                ssum += zz; ssq += zz * zz;
                out1[(size_t)row*STR + v*64 + c] = f2b(zz);
            }
        }
    }

    __syncthreads();
    redL[g*64+c] = ssum; redL[256+g*64+c] = ssq;
    __syncthreads();
    if (tid < 64) {
        float s = redL[tid] + redL[64+tid] + redL[128+tid] + redL[192+tid];
        p1[(size_t)blockIdx.x*128 + tid] = s;
    } else if (tid < 128) {
        const int cc = tid - 64;
        float s = redL[256+cc] + redL[320+cc] + redL[384+cc] + redL[448+cc];
        p1[(size_t)blockIdx.x*128 + 64 + cc] = s;
    }
}

// ---------------------------------------------------------------------------
// K3/K5: finalize BN stats -> scale/shift per channel
// ---------------------------------------------------------------------------
__global__ void k_bnstats(const float* __restrict__ part, int nblk,
                          const float* __restrict__ gamma, const float* __restrict__ beta,
                          float* __restrict__ scale, float* __restrict__ shift)
{
    __shared__ float redL[512];
    const int tid = threadIdx.x, c = tid & 63, q = tid >> 6;
    float s = 0.0f, ss = 0.0f;
    for (int p = q; p < nblk; p += 4) { s += part[p*128+c]; ss += part[p*128+64+c]; }
    redL[q*64+c] = s; redL[256+q*64+c] = ss;
    __syncthreads();
    if (tid < 64) {
        const float S  = redL[tid] + redL[64+tid] + redL[128+tid] + redL[192+tid];
        const float SS = redL[256+tid] + redL[320+tid] + redL[384+tid] + redL[448+tid];
        const float m   = S / NSTAT;
        const float var = SS / NSTAT - m*m;
        const float rstd = rsqrtf(var + EPS_);
        const float sc = gamma[tid] * rstd;
        scale[tid] = sc;
        shift[tid] = beta[tid] - m * sc;
    }
}

// ---------------------------------------------------------------------------
// K4: temporal, SINGLE pass. h = relu(bn1(out1_low)); sliding band-sum in
// LDS (exact fp32 add/sub of bf16-rounded h); z = hsum@Wt + bt -> bf16 into
// the HIGH half of each fp32 row slot (byte-disjoint from out1 low halves,
// so no in-place hazard and no halo). BN2 partials per block.
// LDS = 32K(ring) + 6.4K(hacc) + 8K(wtp) + 2K = 48.6 KB -> 3 blocks/CU.
// ---------------------------------------------------------------------------
__global__ __launch_bounds__(256) void k4_temporal(
    const u16* out1, const u32* __restrict__ wtPack, const float* __restrict__ bt,
    const float* __restrict__ sc1, const float* __restrict__ sh1,
    u16* zout, float* __restrict__ p2)
{
    __shared__ u16   ring[10*1600];
    __shared__ __align__(16) float haccL[1600];
    __shared__ u32   wtpL[2048];
    __shared__ float redL[512];

    const int tid = threadIdx.x, c = tid & 63, g = tid >> 6;
    const int b = blockIdx.y, t0 = blockIdx.x * 15;
    const float s1 = sc1[c], h1 = sh1[c];
    const float btv = bt[c];

    for (int i2 = tid; i2 < 2048; i2 += 256) wtpL[i2] = wtPack[i2];
    for (int i2 = tid; i2 < 1600; i2 += 256) haccL[i2] = 0.0f;
    __syncthreads();

    float zsum = 0.0f, zsq = 0.0f;

    {   // initial window [t0-4, t0+4]
        int slo = t0 - 4; if (slo < 0) slo = 0;
        const int shi = t0 + 4;            // <= 289
        for (int s = slo; s <= shi; ++s) {
            const u16* xr = &out1[((size_t)b*T_ + s) * STR];
            for (int jj = tid; jj < 1600; jj += 256) {   // jj&63 == c
                float hv = fmaf(b2f(xr[jj]), s1, h1);
                hv = hv > 0.0f ? hv : 0.0f;
                const u16 hb = f2b(hv);
                ring[(s%10)*1600 + jj] = hb;
                haccL[jj] += b2f(hb);
            }
        }
    }
    __syncthreads();

    for (int t = t0; t < t0 + 15; ++t) {
        if (t > t0) {
            const int snew = t + 4, sold = t - 5;
            if (snew < T_) {
                const u16* xr = &out1[((size_t)b*T_ + snew) * STR];
                for (int jj = tid; jj < 1600; jj += 256) {
                    float hv = fmaf(b2f(xr[jj]), s1, h1);
                    hv = hv > 0.0f ? hv : 0.0f;
                    const u16 hb = f2b(hv);
                    ring[(snew%10)*1600 + jj] = hb;
                    haccL[jj] += b2f(hb);
                }
            }
            if (sold >= 0) {
                for (int jj = tid; jj < 1600; jj += 256)
                    haccL[jj] -= b2f(ring[(sold%10)*1600 + jj]);
            }
            __syncthreads();
        }

        float acc[7];
        #pragma unroll
        for (int j = 0; j < 7; ++j) acc[j] = btv;
        #pragma unroll 4
        for (int k4 = 0; k4 < 16; ++k4) {
            const int k = k4 * 4;
            const u32 p0 = wtpL[(k4*2)*64 + c], p1v = wtpL[(k4*2+1)*64 + c];
            const float w0 = plo(p0), w1 = phi(p0);
            const float w2 = plo(p1v), w3 = phi(p1v);
            #pragma unroll
            for (int j = 0; j < 7; ++j) {
                const int v = g + 4*j;
                if (v < 25) {
                    const float4 hv4 = *(const float4*)&haccL[v*64 + k];
                    acc[j] = fmaf(hv4.x, w0, fmaf(hv4.y, w1,
                             fmaf(hv4.z, w2, fmaf(hv4.w, w3, acc[j]))));
                }
            }
        }
        u16* zr = &zout[((size_t)b*T_ + t) * STR + ROWE];   // HIGH half
        #pragma unroll
        for (int j = 0; j < 7; ++j) {
            const int v = g + 4*j;
            if (v < 25) {
                const float zz = acc[j];
                zsum += zz; zsq += zz * zz;
                zr[v*64 + c] = f2b(zz);
            }
        }
        __syncthreads();   // hacc reads done before next window update
    }

    redL[g*64+c] = zsum; redL[256+g*64+c] = zsq;
    __syncthreads();
    const int blk = blockIdx.y * 20 + blockIdx.x;
    if (tid < 64) {
        float s = redL[tid] + redL[64+tid] + redL[128+tid] + redL[192+tid];
        p2[(size_t)blk*128 + tid] = s;
    } else if (tid < 128) {
        const int cc = tid - 64;
        float s = redL[256+cc] + redL[320+cc] + redL[384+cc] + redL[448+cc];
        p2[(size_t)blk*128 + 64 + cc] = s;
    }
}

// ---------------------------------------------------------------------------
// K6: per-row in-place finalize. Read z bf16 from high half into regs,
// barrier, write relu(bn2(z)) as fp32 over the full row. One block per row.
// ---------------------------------------------------------------------------
__global__ __launch_bounds__(256) void k6_final(
    u16* rowsbuf, const float* __restrict__ sc2, const float* __restrict__ sh2)
{
    __shared__ float sL[64], hL[64];
    const int tid = threadIdx.x;
    if (tid < 64) { sL[tid] = sc2[tid]; hL[tid] = sh2[tid]; }

    const size_t base = (size_t)blockIdx.x * STR;
    float vals[8];
    const int e0 = tid * 8;
    if (tid < 200) {
        const uint4 zv = *(const uint4*)&rowsbuf[base + ROWE + e0];
        const u32 zz[4] = { zv.x, zv.y, zv.z, zv.w };
        #pragma unroll
        for (int m = 0; m < 4; ++m) {
            vals[2*m]   = plo(zz[m]);
            vals[2*m+1] = phi(zz[m]);
        }
    }
    __syncthreads();
    if (tid < 200) {
        const int c0 = e0 & 63;
        float* frow = (float*)&rowsbuf[base];
        float4 o0, o1;
        float* ov0 = (float*)&o0; float* ov1 = (float*)&o1;
        #pragma unroll
        for (int m = 0; m < 4; ++m) {
            float r = fmaf(vals[m], sL[c0+m], hL[c0+m]);
            ov0[m] = r > 0.0f ? r : 0.0f;
        }
        #pragma unroll
        for (int m = 0; m < 4; ++m) {
            float r = fmaf(vals[4+m], sL[c0+4+m], hL[c0+4+m]);
            ov1[m] = r > 0.0f ? r : 0.0f;
        }
        *(float4*)&frow[e0]     = o0;
        *(float4*)&frow[e0 + 4] = o1;
    }
}

// ---------------------------------------------------------------------------
extern "C" void kernel_launch(void* const* d_in, const int* in_sizes, int n_in,
                              void* d_out, int out_size, void* d_ws, size_t ws_size,
                              hipStream_t stream)
{
    const float* x     = (const float*)d_in[0];
    const float* A     = (const float*)d_in[1];
    const float* E     = (const float*)d_in[2];
    const float* W1    = (const float*)d_in[3];
    const float* b1    = (const float*)d_in[4];
    const float* W2    = (const float*)d_in[5];
    const float* b2    = (const float*)d_in[6];
    const float* W3    = (const float*)d_in[7];
    const float* b3    = (const float*)d_in[8];
    const float* Wt    = (const float*)d_in[9];
    const float* bt    = (const float*)d_in[10];
    const float* gamma = (const float*)d_in[11];
    const float* beta  = (const float*)d_in[12];

    u16* rowsbuf = (u16*)d_out;       // per-row slots: low half out1, high half z

    // ws layout — front of d_ws; total ≈ 5.7 MB.
    float* wsf   = (float*)d_ws;
    float* an    = wsf;               // 2112
    float* bsum  = an + 2112;         // 64
    float* sc1   = bsum + 64;
    float* sh1   = sc1 + 64;
    float* sc2   = sh1 + 64;
    float* sh2   = sc2 + 64;
    u32*  wPack  = (u32*)(sh2 + 64);  // 3*2048
    u32*  wtPack = wPack + 6144;      // 2048
    float* p1    = (float*)(wtPack + 2048);  // 9600*128
    float* p2    = p1 + 9600*128;            // 1280*128

    hipLaunchKernelGGL(k1_prep, dim3(1), dim3(128), 0, stream,
                       A, E, b1, b2, b3, W1, W2, W3, Wt, an, bsum, wPack, wtPack);
    hipLaunchKernelGGL(k2_spatial, dim3(9600), dim3(256), 0, stream,
                       x, wPack, an, bsum, rowsbuf, p1);
    hipLaunchKernelGGL(k_bnstats, dim3(1), dim3(256), 0, stream,
                       p1, 9600, gamma, beta, sc1, sh1);
    hipLaunchKernelGGL(k4_temporal, dim3(20, 64), dim3(256), 0, stream,
                       rowsbuf, wtPack, bt, sc1, sh1, rowsbuf, p2);
    hipLaunchKernelGGL(k_bnstats, dim3(1), dim3(256), 0, stream,
                       p2, 1280, gamma, beta, sc2, sh2);
    hipLaunchKernelGGL(k6_final, dim3(ROWS), dim3(256), 0, stream,
                       rowsbuf, sc2, sh2);
}